// Round 6
// baseline (480.667 us; speedup 1.0000x reference)
//
#include <hip/hip_runtime.h>
#include <hip/hip_cooperative_groups.h>
#include <stdint.h>
#include <stddef.h>

namespace cg = cooperative_groups;

// Problem constants (from reference): B=8, L=8192, D=1024, M=L/4=2048.
// Setup guarantees exactly M true mask positions per row -> counts == M.
#define B_ 8
#define L_ 8192
#define D_ 1024
#define M_ 2048
#define S_ 128           // segments per row
#define G_ 16            // M_/S_  (segment length)
#define D4_ (D_/4)
#define NBLK_ (B_*S_)    // 1024 blocks

typedef float f4 __attribute__((ext_vector_type(4)));

// ---------------- workspace layout (bytes) ----------------
#define OFF_POS    ((size_t)0)
#define OFF_DEC    (OFF_POS  + (size_t)B_*M_*4)
#define OFF_A      (OFF_DEC  + (size_t)B_*M_*4)
#define OFF_EZ     (OFF_A    + (size_t)B_*S_*4)
#define OFF_HINIT  (OFF_EZ   + (size_t)B_*S_*D_*4)
#define WS_TOTAL   (OFF_HINIT + (size_t)B_*S_*D_*4)

// ============================================================================
// Cooperative mega-kernel: compact -> segend(x into regs) -> combine -> scatter
// Grid 1024 x 256, 4 blocks/CU co-resident (launch_bounds caps VGPR at 128).
// ============================================================================
__global__ __launch_bounds__(256, 4)
void mega_kernel(const f4* __restrict__ x4,
                 const f4* __restrict__ res4,
                 const float* __restrict__ prob,
                 const void* __restrict__ mask_raw,
                 const float* __restrict__ state,
                 int* __restrict__ pos,
                 float* __restrict__ dec,
                 float* __restrict__ Aseg,
                 float* __restrict__ ez,
                 float* __restrict__ hinit,
                 f4* __restrict__ out4,
                 float* __restrict__ newstate) {
    cg::grid_group grid = cg::this_grid();
    const int blk = blockIdx.x;         // b*S_ + s
    const int t = threadIdx.x;

    __shared__ int   u8flag;
    __shared__ int   wsum[4];
    __shared__ int   woff[4];
    __shared__ int   pl[G_ + 1];
    __shared__ float dl[G_];
    __shared__ float Al[S_];

    // ---------------- phase 0: compact (blocks 0..7) ----------------
    if (blk < B_) {
        const int b = blk;
        // mask dtype detection from first 8 KiB (u8 bools reinterpreted as u32
        // give values > 1 somewhere; int32 {0,1} never do)
        if (t == 0) u8flag = 0;
        __syncthreads();
        {
            const uint32_t* mu = (const uint32_t*)mask_raw;
            uint32_t orv = 0;
            #pragma unroll
            for (int j = 0; j < 8; j++) orv |= mu[t * 8 + j];
            if (orv > 1u) atomicOr(&u8flag, 1);
        }
        __syncthreads();
        const bool u8 = (u8flag != 0);

        const int base_l = t * 32;
        int cnt = 0;
        if (u8) {
            const uint8_t* mrow = (const uint8_t*)mask_raw + (size_t)b * L_;
            #pragma unroll
            for (int j = 0; j < 32; j++) cnt += mrow[base_l + j] ? 1 : 0;
        } else {
            const int* mrow = (const int*)mask_raw + (size_t)b * L_;
            #pragma unroll
            for (int j = 0; j < 32; j++) cnt += mrow[base_l + j] ? 1 : 0;
        }
        // exclusive scan of per-thread counts (4 waves x 64 lanes)
        const int lane = t & 63, wid = t >> 6;
        int v = cnt;
        #pragma unroll
        for (int off = 1; off < 64; off <<= 1) {
            int n = __shfl_up(v, off, 64);
            if (lane >= off) v += n;
        }
        if (lane == 63) wsum[wid] = v;
        __syncthreads();
        if (t < 4) {
            int acc = 0;
            for (int w = 0; w < t; w++) acc += wsum[w];
            woff[t] = acc;
        }
        __syncthreads();
        int run = (v - cnt) + woff[wid];

        const float* prow = prob + (size_t)b * L_;
        if (u8) {
            const uint8_t* mrow = (const uint8_t*)mask_raw + (size_t)b * L_;
            for (int j = 0; j < 32; j++) {
                const int l = base_l + j;
                if (mrow[l]) {
                    float d = fminf(fmaxf(1.0f - prow[l], 0.0f), 1.0f);
                    pos[(size_t)b * M_ + run] = l;
                    dec[(size_t)b * M_ + run] = d;
                    run++;
                }
            }
        } else {
            const int* mrow = (const int*)mask_raw + (size_t)b * L_;
            for (int j = 0; j < 32; j++) {
                const int l = base_l + j;
                if (mrow[l]) {
                    float d = fminf(fmaxf(1.0f - prow[l], 0.0f), 1.0f);
                    pos[(size_t)b * M_ + run] = l;
                    dec[(size_t)b * M_ + run] = d;
                    run++;
                }
            }
        }
        __threadfence();
    }
    grid.sync();

    // ---------------- phase 1: segment scan, x gathered into registers ------
    const int b = blk >> 7;             // S_ = 128
    const int s = blk & (S_ - 1);
    if (t < G_) {
        pl[t] = pos[(size_t)b * M_ + s * G_ + t];
        dl[t] = dec[(size_t)b * M_ + s * G_ + t];
    }
    if (t == 0) {
        pl[G_] = (s == S_ - 1) ? L_ : pos[(size_t)b * M_ + (s + 1) * G_];
    }
    __syncthreads();

    const f4* xrow = x4 + (size_t)b * L_ * D4_;
    f4 xr[G_];                           // 64 VGPRs; statically indexed (full unroll)
    f4 h = (f4)(0.0f);
    #pragma unroll
    for (int m = 0; m < G_; m++) {
        xr[m] = xrow[(size_t)pl[m] * D4_ + t];
        const float d = dl[m];
        h = d * h + (1.0f - d) * xr[m];
    }
    ((f4*)ez)[(size_t)blk * D4_ + t] = h;
    if (t == 0) {
        float p = 1.0f;
        #pragma unroll
        for (int m = 0; m < G_; m++) p *= dl[m];
        Aseg[blk] = p;
    }
    __threadfence();
    grid.sync();

    // ---------------- phase 2: carry scan across segments (blocks 0..31) ----
    if (blk < 32) {
        const int b2 = blk >> 2;
        const int ch = ((blk & 3) << 8) + t;    // scalar channel 0..1023
        if (t < S_) Al[t] = Aseg[b2 * S_ + t];
        __syncthreads();
        float c = state[(size_t)b2 * D_ + ch];
        for (int s0 = 0; s0 < S_; s0 += 8) {
            float e[8];
            #pragma unroll
            for (int j = 0; j < 8; j++)
                e[j] = ez[((size_t)b2 * S_ + s0 + j) * D_ + ch];
            #pragma unroll
            for (int j = 0; j < 8; j++) {
                hinit[((size_t)b2 * S_ + s0 + j) * D_ + ch] = c;
                c = fmaf(Al[s0 + j], c, e[j]);
            }
        }
        newstate[(size_t)b2 * D_ + ch] = c;     // counts == M guaranteed
        __threadfence();
    }
    grid.sync();

    // ---------------- phase 3: run-scatter detokenizer (x from registers) ---
    const f4* resrow = res4 + (size_t)b * L_ * D4_;
    f4*       outrow = out4 + (size_t)b * L_ * D4_;

    if (s == 0) {                        // prefix [0, pos[0)): pure residual
        const int p0 = pl[0];
        int l = 0;
        for (; l + 2 <= p0; l += 2) {
            f4 r0 = __builtin_nontemporal_load(resrow + (size_t)(l + 0) * D4_ + t);
            f4 r1 = __builtin_nontemporal_load(resrow + (size_t)(l + 1) * D4_ + t);
            __builtin_nontemporal_store(r0, outrow + (size_t)(l + 0) * D4_ + t);
            __builtin_nontemporal_store(r1, outrow + (size_t)(l + 1) * D4_ + t);
        }
        if (l < p0) {
            f4 r = __builtin_nontemporal_load(resrow + (size_t)l * D4_ + t);
            __builtin_nontemporal_store(r, outrow + (size_t)l * D4_ + t);
        }
    }

    f4 h3 = ((const f4*)hinit)[(size_t)blk * D4_ + t];
    #pragma unroll
    for (int m = 0; m < G_; m++) {
        const float d = dl[m];
        h3 = d * h3 + (1.0f - d) * xr[m];
        const int lend = pl[m + 1];
        int l = pl[m];
        for (; l + 2 <= lend; l += 2) {
            f4 r0 = __builtin_nontemporal_load(resrow + (size_t)(l + 0) * D4_ + t);
            f4 r1 = __builtin_nontemporal_load(resrow + (size_t)(l + 1) * D4_ + t);
            r0 += h3; r1 += h3;
            __builtin_nontemporal_store(r0, outrow + (size_t)(l + 0) * D4_ + t);
            __builtin_nontemporal_store(r1, outrow + (size_t)(l + 1) * D4_ + t);
        }
        if (l < lend) {
            f4 r = __builtin_nontemporal_load(resrow + (size_t)l * D4_ + t);
            r += h3;
            __builtin_nontemporal_store(r, outrow + (size_t)l * D4_ + t);
        }
    }
}

// ============================================================================
// Fallback path (round-5 4-kernel pipeline) in case cooperative launch fails.
// ============================================================================
__global__ __launch_bounds__(1024)
void compact_kernel(const void* __restrict__ mask_raw,
                    const float* __restrict__ prob,
                    int* __restrict__ pos,
                    float* __restrict__ dec) {
    const int b = blockIdx.x;
    const int t = threadIdx.x;
    __shared__ int u8flag;
    if (t == 0) u8flag = 0;
    __syncthreads();
    {
        const uint32_t* mu = (const uint32_t*)mask_raw;
        uint32_t w0 = mu[t * 2], w1 = mu[t * 2 + 1];
        if (w0 > 1u || w1 > 1u) atomicOr(&u8flag, 1);
    }
    __syncthreads();
    const bool u8 = (u8flag != 0);
    int mv[8];
    const int base_l = t * 8;
    if (u8) {
        const uint8_t* mrow = (const uint8_t*)mask_raw + (size_t)b * L_;
        #pragma unroll
        for (int j = 0; j < 8; j++) mv[j] = mrow[base_l + j] ? 1 : 0;
    } else {
        const int* mrow = (const int*)mask_raw + (size_t)b * L_;
        #pragma unroll
        for (int j = 0; j < 8; j++) mv[j] = mrow[base_l + j] ? 1 : 0;
    }
    int tsum = 0;
    #pragma unroll
    for (int j = 0; j < 8; j++) tsum += mv[j];
    const int lane = t & 63, wid = t >> 6;
    int v = tsum;
    #pragma unroll
    for (int off = 1; off < 64; off <<= 1) {
        int n = __shfl_up(v, off, 64);
        if (lane >= off) v += n;
    }
    __shared__ int wsum[16];
    __shared__ int woff[16];
    if (lane == 63) wsum[wid] = v;
    __syncthreads();
    if (t < 16) {
        int acc = 0;
        for (int w = 0; w < t; w++) acc += wsum[w];
        woff[t] = acc;
    }
    __syncthreads();
    int run = (v - tsum) + woff[wid];
    const float* prow = prob + (size_t)b * L_;
    #pragma unroll
    for (int j = 0; j < 8; j++) {
        const int l = base_l + j;
        if (mv[j]) {
            float d = fminf(fmaxf(1.0f - prow[l], 0.0f), 1.0f);
            pos[(size_t)b * M_ + run] = l;
            dec[(size_t)b * M_ + run] = d;
            run += 1;
        }
    }
}

__global__ __launch_bounds__(256)
void segend_kernel(const f4* __restrict__ x4,
                   const int* __restrict__ pos,
                   const float* __restrict__ dec,
                   f4* __restrict__ ez4,
                   float* __restrict__ Aseg) {
    const int blk = blockIdx.x;
    const int b = blk / S_, s = blk % S_;
    const int t = threadIdx.x;
    __shared__ int   pl[G_];
    __shared__ float dl[G_];
    if (t < G_) {
        pl[t] = pos[(size_t)b * M_ + (size_t)s * G_ + t];
        dl[t] = dec[(size_t)b * M_ + (size_t)s * G_ + t];
    }
    __syncthreads();
    f4 h = (f4)(0.0f);
    #pragma unroll
    for (int m = 0; m < G_; m++) {
        const float d = dl[m];
        const f4 xv = x4[((size_t)b * L_ + pl[m]) * D4_ + t];
        h = d * h + (1.0f - d) * xv;
    }
    ez4[((size_t)b * S_ + s) * D4_ + t] = h;
    if (t == 0) {
        float p = 1.0f;
        #pragma unroll
        for (int m = 0; m < G_; m++) p *= dl[m];
        Aseg[b * S_ + s] = p;
    }
}

__global__ __launch_bounds__(64)
void combine_kernel(const float* __restrict__ ez,
                    const float* __restrict__ Aseg,
                    const float* __restrict__ state,
                    float* __restrict__ hinit,
                    float* __restrict__ newstate) {
    const int b = blockIdx.x;
    const int ch = blockIdx.y * 64 + threadIdx.x;
    __shared__ float Al[S_];
    Al[threadIdx.x] = Aseg[b * S_ + threadIdx.x];
    Al[threadIdx.x + 64] = Aseg[b * S_ + threadIdx.x + 64];
    __syncthreads();
    float c = state[(size_t)b * D_ + ch];
    for (int s0 = 0; s0 < S_; s0 += 8) {
        float e[8];
        #pragma unroll
        for (int j = 0; j < 8; j++)
            e[j] = ez[((size_t)b * S_ + s0 + j) * D_ + ch];
        #pragma unroll
        for (int j = 0; j < 8; j++) {
            hinit[((size_t)b * S_ + s0 + j) * D_ + ch] = c;
            c = fmaf(Al[s0 + j], c, e[j]);
        }
    }
    newstate[(size_t)b * D_ + ch] = c;
}

__global__ __launch_bounds__(256)
void fused_kernel(const f4* __restrict__ x4,
                  const f4* __restrict__ res4,
                  const int* __restrict__ pos,
                  const float* __restrict__ dec,
                  const f4* __restrict__ hinit4,
                  f4* __restrict__ out4) {
    const int blk = blockIdx.x;
    const int b = blk / S_, s = blk % S_;
    const int t = threadIdx.x;
    __shared__ int   pl[G_ + 1];
    __shared__ float dl[G_];
    if (t < G_) {
        pl[t] = pos[(size_t)b * M_ + (size_t)s * G_ + t];
        dl[t] = dec[(size_t)b * M_ + (size_t)s * G_ + t];
    }
    if (t == 0) {
        pl[G_] = (s == S_ - 1) ? L_ : pos[(size_t)b * M_ + (size_t)(s + 1) * G_];
    }
    __syncthreads();
    const f4* xrow   = x4   + (size_t)b * L_ * D4_;
    const f4* resrow = res4 + (size_t)b * L_ * D4_;
    f4*       outrow = out4 + (size_t)b * L_ * D4_;
    if (s == 0) {
        const int p0 = pl[0];
        for (int l = 0; l < p0; l++) {
            f4 r = __builtin_nontemporal_load(resrow + (size_t)l * D4_ + t);
            __builtin_nontemporal_store(r, outrow + (size_t)l * D4_ + t);
        }
    }
    f4 h = hinit4[((size_t)b * S_ + s) * D4_ + t];
    #pragma unroll
    for (int m = 0; m < G_; m++) {
        const float d = dl[m];
        const f4 xv = xrow[(size_t)pl[m] * D4_ + t];
        h = d * h + (1.0f - d) * xv;
        const int lend = pl[m + 1];
        for (int l = pl[m]; l < lend; l++) {
            f4 r = __builtin_nontemporal_load(resrow + (size_t)l * D4_ + t);
            r += h;
            __builtin_nontemporal_store(r, outrow + (size_t)l * D4_ + t);
        }
    }
}

extern "C" void kernel_launch(void* const* d_in, const int* in_sizes, int n_in,
                              void* d_out, int out_size, void* d_ws, size_t ws_size,
                              hipStream_t stream) {
    const float* x        = (const float*)d_in[0];
    const float* residual = (const float*)d_in[1];
    const float* prob     = (const float*)d_in[2];
    const void*  mask     = d_in[3];
    const float* state    = (const float*)d_in[4];

    float* out       = (float*)d_out;                       // (B,L,D)
    float* new_state = out + (size_t)B_ * L_ * D_;          // (B,D)

    if (ws_size < WS_TOTAL) return;

    char* ws = (char*)d_ws;
    int*   pos   = (int*)  (ws + OFF_POS);
    float* dec   = (float*)(ws + OFF_DEC);
    float* Aseg  = (float*)(ws + OFF_A);
    float* ez    = (float*)(ws + OFF_EZ);
    float* hinit = (float*)(ws + OFF_HINIT);

    const f4* x4   = (const f4*)x;
    const f4* res4 = (const f4*)residual;
    f4*       out4 = (f4*)out;

    void* args[] = {
        (void*)&x4, (void*)&res4, (void*)&prob, (void*)&mask, (void*)&state,
        (void*)&pos, (void*)&dec, (void*)&Aseg, (void*)&ez, (void*)&hinit,
        (void*)&out4, (void*)&new_state
    };
    hipError_t err = hipLaunchCooperativeKernel(
        (const void*)mega_kernel, dim3(NBLK_), dim3(256), args, 0, stream);

    if (err != hipSuccess) {
        // fallback: 4-kernel pipeline (round-5 verified path)
        compact_kernel<<<B_, 1024, 0, stream>>>(mask, prob, pos, dec);
        segend_kernel<<<B_ * S_, 256, 0, stream>>>(x4, pos, dec, (f4*)ez, Aseg);
        combine_kernel<<<dim3(B_, 16), 64, 0, stream>>>(ez, Aseg, state, hinit, new_state);
        fused_kernel<<<B_ * S_, 256, 0, stream>>>(x4, res4, pos, dec, (const f4*)hinit, out4);
    }
}

// Round 7
// 154.238 us; speedup vs baseline: 3.1164x; 3.1164x over previous
//
#include <hip/hip_runtime.h>
#include <stdint.h>
#include <stddef.h>

// Problem constants (from reference): B=8, L=8192, D=1024, M=L/4=2048.
// Setup guarantees exactly M true mask positions per row -> counts == M.
#define B_ 8
#define L_ 8192
#define D_ 1024
#define M_ 2048
#define S_ 256           // segments per row (2048 blocks -> 8 blocks/CU, 100% occ)
#define G_ 8             // M_/S_  (segment length)
#define D4_ (D_/4)

typedef float f4 __attribute__((ext_vector_type(4)));   // native vec4 (nontemporal-capable)

// ---------------- workspace layout (bytes) ----------------
#define OFF_POS    ((size_t)0)
#define OFF_DEC    (OFF_POS  + (size_t)B_*M_*4)
#define OFF_A      (OFF_DEC  + (size_t)B_*M_*4)
#define OFF_EZ     (OFF_A    + (size_t)B_*S_*4)
#define OFF_HINIT  (OFF_EZ   + (size_t)B_*S_*D_*4)
#define WS_TOTAL   (OFF_HINIT + (size_t)B_*S_*D_*4)

// ---------------- kernel 1: per-row compaction (prefix sum over mask) -------
// One block (1024 threads) per batch row; each thread owns 8 consecutive l.
// Mask dtype (1-byte bool vs int32) detected in-block from the first 8 KiB.
__global__ __launch_bounds__(1024)
void compact_kernel(const void* __restrict__ mask_raw,
                    const float* __restrict__ prob,
                    int* __restrict__ pos,
                    float* __restrict__ dec) {
    const int b = blockIdx.x;
    const int t = threadIdx.x;

    __shared__ int u8flag;
    if (t == 0) u8flag = 0;
    __syncthreads();
    {
        const uint32_t* mu = (const uint32_t*)mask_raw;
        uint32_t w0 = mu[t * 2], w1 = mu[t * 2 + 1];
        if (w0 > 1u || w1 > 1u) atomicOr(&u8flag, 1);
    }
    __syncthreads();
    const bool u8 = (u8flag != 0);

    int mv[8];
    const int base_l = t * 8;
    if (u8) {
        const uint8_t* mrow = (const uint8_t*)mask_raw + (size_t)b * L_;
        #pragma unroll
        for (int j = 0; j < 8; j++) mv[j] = mrow[base_l + j] ? 1 : 0;
    } else {
        const int* mrow = (const int*)mask_raw + (size_t)b * L_;
        #pragma unroll
        for (int j = 0; j < 8; j++) mv[j] = mrow[base_l + j] ? 1 : 0;
    }
    int tsum = 0;
    #pragma unroll
    for (int j = 0; j < 8; j++) tsum += mv[j];

    // block-wide exclusive scan of per-thread sums (wave64 x 16 waves)
    const int lane = t & 63, wid = t >> 6;
    int v = tsum;
    #pragma unroll
    for (int off = 1; off < 64; off <<= 1) {
        int n = __shfl_up(v, off, 64);
        if (lane >= off) v += n;
    }
    __shared__ int wsum[16];
    __shared__ int woff[16];
    if (lane == 63) wsum[wid] = v;
    __syncthreads();
    if (t < 16) {
        int acc = 0;
        for (int w = 0; w < t; w++) acc += wsum[w];
        woff[t] = acc;
    }
    __syncthreads();
    int run = (v - tsum) + woff[wid];   // exclusive prefix for this thread

    const float* prow = prob + (size_t)b * L_;
    #pragma unroll
    for (int j = 0; j < 8; j++) {
        const int l = base_l + j;
        if (mv[j]) {
            float d = 1.0f - prow[l];
            d = fminf(fmaxf(d, 0.0f), 1.0f);
            pos[(size_t)b * M_ + run] = l;
            dec[(size_t)b * M_ + run] = d;
            run += 1;
        }
    }
}

// ---------------- kernel 2: zero-init segment END values + decay products ---
// One block per (b, segment); 256 threads x f4 = full D row. Fully unrolled so
// the compiler hoists the 8 independent gather loads.
__global__ __launch_bounds__(256)
void segend_kernel(const f4* __restrict__ x4,
                   const int* __restrict__ pos,
                   const float* __restrict__ dec,
                   f4* __restrict__ ez4,
                   float* __restrict__ Aseg) {
    const int blk = blockIdx.x;          // b*S_ + s
    const int b = blk / S_, s = blk % S_;
    const int t = threadIdx.x;
    __shared__ int   pl[G_];
    __shared__ float dl[G_];
    if (t < G_) {
        pl[t] = pos[(size_t)b * M_ + (size_t)s * G_ + t];
        dl[t] = dec[(size_t)b * M_ + (size_t)s * G_ + t];
    }
    __syncthreads();
    f4 h = (f4)(0.0f);
    #pragma unroll
    for (int m = 0; m < G_; m++) {
        const float d = dl[m];
        const f4 xv = x4[((size_t)b * L_ + pl[m]) * D4_ + t];
        h = d * h + (1.0f - d) * xv;
    }
    ez4[(size_t)blk * D4_ + t] = h;
    if (t == 0) {
        float p = 1.0f;
        #pragma unroll
        for (int m = 0; m < G_; m++) p *= dl[m];
        Aseg[blk] = p;
    }
}

// ---------------- kernel 3: carry propagation across segments + new_state ---
// grid (B, 16), block 64: scalar channel per thread (8192 parallel chains).
// ez prefetched in batches of 8 (statically indexed regs) so the serial FMA
// chain stalls once per 8 steps instead of every step.
__global__ __launch_bounds__(64)
void combine_kernel(const float* __restrict__ ez,
                    const float* __restrict__ Aseg,
                    const float* __restrict__ state,
                    float* __restrict__ hinit,
                    float* __restrict__ newstate) {
    const int b = blockIdx.x;
    const int ch = blockIdx.y * 64 + threadIdx.x;   // scalar channel 0..1023
    __shared__ float Al[S_];
    for (int i = threadIdx.x; i < S_; i += 64) Al[i] = Aseg[b * S_ + i];
    __syncthreads();

    float c = state[(size_t)b * D_ + ch];
    for (int s0 = 0; s0 < S_; s0 += 8) {
        float e[8];
        #pragma unroll
        for (int j = 0; j < 8; j++)
            e[j] = ez[((size_t)b * S_ + s0 + j) * D_ + ch];
        #pragma unroll
        for (int j = 0; j < 8; j++) {
            hinit[((size_t)b * S_ + s0 + j) * D_ + ch] = c;
            c = fmaf(Al[s0 + j], c, e[j]);
        }
    }
    newstate[(size_t)b * D_ + ch] = c;   // counts == M guaranteed
}

// ---------------- kernel 4: fused scan + run-scatter detokenizer ------------
// One block (256 threads, full D) per (b, segment). Recomputes the in-segment
// scan from hinit; for each run [pos[m], pos[m+1)) writes
// out[l] = residual[l] + h. Row loop unrolled x4 (4 NT loads in flight);
// next run's x row prefetched under the current run's scatter.
__global__ __launch_bounds__(256)
void fused_kernel(const f4* __restrict__ x4,
                  const f4* __restrict__ res4,
                  const int* __restrict__ pos,
                  const float* __restrict__ dec,
                  const f4* __restrict__ hinit4,
                  f4* __restrict__ out4) {
    const int blk = blockIdx.x;          // b*S_ + s
    const int b = blk / S_, s = blk % S_;
    const int t = threadIdx.x;
    __shared__ int   pl[G_ + 1];
    __shared__ float dl[G_];
    if (t < G_) {
        pl[t] = pos[(size_t)b * M_ + (size_t)s * G_ + t];
        dl[t] = dec[(size_t)b * M_ + (size_t)s * G_ + t];
    }
    if (t == 0) {
        pl[G_] = (s == S_ - 1) ? L_ : pos[(size_t)b * M_ + (size_t)(s + 1) * G_];
    }
    __syncthreads();

    const f4* xrow   = x4   + (size_t)b * L_ * D4_;
    const f4* resrow = res4 + (size_t)b * L_ * D4_;
    f4*       outrow = out4 + (size_t)b * L_ * D4_;

    // prefix [0, pos[0]) of the batch row: ci < 0 -> pure residual
    if (s == 0) {
        const int p0 = pl[0];
        int l = 0;
        for (; l + 4 <= p0; l += 4) {
            f4 r0 = __builtin_nontemporal_load(resrow + (size_t)(l + 0) * D4_ + t);
            f4 r1 = __builtin_nontemporal_load(resrow + (size_t)(l + 1) * D4_ + t);
            f4 r2 = __builtin_nontemporal_load(resrow + (size_t)(l + 2) * D4_ + t);
            f4 r3 = __builtin_nontemporal_load(resrow + (size_t)(l + 3) * D4_ + t);
            __builtin_nontemporal_store(r0, outrow + (size_t)(l + 0) * D4_ + t);
            __builtin_nontemporal_store(r1, outrow + (size_t)(l + 1) * D4_ + t);
            __builtin_nontemporal_store(r2, outrow + (size_t)(l + 2) * D4_ + t);
            __builtin_nontemporal_store(r3, outrow + (size_t)(l + 3) * D4_ + t);
        }
        for (; l < p0; l++) {
            f4 r = __builtin_nontemporal_load(resrow + (size_t)l * D4_ + t);
            __builtin_nontemporal_store(r, outrow + (size_t)l * D4_ + t);
        }
    }

    f4 h  = hinit4[(size_t)blk * D4_ + t];
    f4 xv = xrow[(size_t)pl[0] * D4_ + t];
    for (int m = 0; m < G_; m++) {
        f4 xn = xv;
        if (m < G_ - 1) xn = xrow[(size_t)pl[m + 1] * D4_ + t];  // prefetch next run's x
        const float d = dl[m];
        const float w = 1.0f - d;
        h = d * h + w * xv;
        const int lend = pl[m + 1];
        int l = pl[m];
        for (; l + 4 <= lend; l += 4) {
            f4 r0 = __builtin_nontemporal_load(resrow + (size_t)(l + 0) * D4_ + t);
            f4 r1 = __builtin_nontemporal_load(resrow + (size_t)(l + 1) * D4_ + t);
            f4 r2 = __builtin_nontemporal_load(resrow + (size_t)(l + 2) * D4_ + t);
            f4 r3 = __builtin_nontemporal_load(resrow + (size_t)(l + 3) * D4_ + t);
            r0 += h; r1 += h; r2 += h; r3 += h;
            __builtin_nontemporal_store(r0, outrow + (size_t)(l + 0) * D4_ + t);
            __builtin_nontemporal_store(r1, outrow + (size_t)(l + 1) * D4_ + t);
            __builtin_nontemporal_store(r2, outrow + (size_t)(l + 2) * D4_ + t);
            __builtin_nontemporal_store(r3, outrow + (size_t)(l + 3) * D4_ + t);
        }
        for (; l < lend; l++) {
            f4 r = __builtin_nontemporal_load(resrow + (size_t)l * D4_ + t);
            r += h;
            __builtin_nontemporal_store(r, outrow + (size_t)l * D4_ + t);
        }
        xv = xn;
    }
}

extern "C" void kernel_launch(void* const* d_in, const int* in_sizes, int n_in,
                              void* d_out, int out_size, void* d_ws, size_t ws_size,
                              hipStream_t stream) {
    const float* x        = (const float*)d_in[0];
    const float* residual = (const float*)d_in[1];
    const float* prob     = (const float*)d_in[2];
    const void*  mask     = d_in[3];
    const float* state    = (const float*)d_in[4];

    float* out       = (float*)d_out;                       // (B,L,D)
    float* new_state = out + (size_t)B_ * L_ * D_;          // (B,D)

    if (ws_size < WS_TOTAL) return;  // fail loudly (zeros) rather than corrupt

    char* ws = (char*)d_ws;
    int*   pos   = (int*)  (ws + OFF_POS);
    float* dec   = (float*)(ws + OFF_DEC);
    float* Aseg  = (float*)(ws + OFF_A);
    float* ez    = (float*)(ws + OFF_EZ);
    float* hinit = (float*)(ws + OFF_HINIT);

    compact_kernel<<<B_, 1024, 0, stream>>>(mask, prob, pos, dec);

    segend_kernel<<<B_ * S_, 256, 0, stream>>>(
        (const f4*)x, pos, dec, (f4*)ez, Aseg);

    combine_kernel<<<dim3(B_, 16), 64, 0, stream>>>(
        ez, Aseg, state, hinit, new_state);

    fused_kernel<<<B_ * S_, 256, 0, stream>>>(
        (const f4*)x, (const f4*)residual, pos, dec,
        (const f4*)hinit, (f4*)out);
}

// Round 8
// 146.817 us; speedup vs baseline: 3.2739x; 1.0505x over previous
//
#include <hip/hip_runtime.h>
#include <stdint.h>
#include <stddef.h>

// Problem constants (from reference): B=8, L=8192, D=1024, M=L/4=2048.
// Setup guarantees exactly M true mask positions per row -> counts == M.
#define B_ 8
#define L_ 8192
#define D_ 1024
#define M_ 2048
#define S_ 128           // segments per row
#define G_ 16            // M_/S_  (segment length)
#define D4_ (D_/4)

typedef float f4 __attribute__((ext_vector_type(4)));   // native vec4 (nontemporal-capable)

// ---------------- workspace layout (bytes) ----------------
#define OFF_POS    ((size_t)0)
#define OFF_DEC    (OFF_POS  + (size_t)B_*M_*4)
#define OFF_A      (OFF_DEC  + (size_t)B_*M_*4)
#define OFF_EZ     (OFF_A    + (size_t)B_*S_*4)
#define OFF_HINIT  (OFF_EZ   + (size_t)B_*S_*D_*4)
#define WS_TOTAL   (OFF_HINIT + (size_t)B_*S_*D_*4)

// ---------------- kernel 1: per-row compaction (prefix sum over mask) -------
// One block (1024 threads) per batch row; each thread owns 8 consecutive l.
// Mask dtype (1-byte bool vs int32) detected in-block from the first 8 KiB.
__global__ __launch_bounds__(1024)
void compact_kernel(const void* __restrict__ mask_raw,
                    const float* __restrict__ prob,
                    int* __restrict__ pos,
                    float* __restrict__ dec) {
    const int b = blockIdx.x;
    const int t = threadIdx.x;

    __shared__ int u8flag;
    if (t == 0) u8flag = 0;
    __syncthreads();
    {
        const uint32_t* mu = (const uint32_t*)mask_raw;
        uint32_t w0 = mu[t * 2], w1 = mu[t * 2 + 1];
        if (w0 > 1u || w1 > 1u) atomicOr(&u8flag, 1);
    }
    __syncthreads();
    const bool u8 = (u8flag != 0);

    int mv[8];
    const int base_l = t * 8;
    if (u8) {
        const uint8_t* mrow = (const uint8_t*)mask_raw + (size_t)b * L_;
        #pragma unroll
        for (int j = 0; j < 8; j++) mv[j] = mrow[base_l + j] ? 1 : 0;
    } else {
        const int* mrow = (const int*)mask_raw + (size_t)b * L_;
        #pragma unroll
        for (int j = 0; j < 8; j++) mv[j] = mrow[base_l + j] ? 1 : 0;
    }
    int tsum = 0;
    #pragma unroll
    for (int j = 0; j < 8; j++) tsum += mv[j];

    // block-wide exclusive scan of per-thread sums (wave64 x 16 waves)
    const int lane = t & 63, wid = t >> 6;
    int v = tsum;
    #pragma unroll
    for (int off = 1; off < 64; off <<= 1) {
        int n = __shfl_up(v, off, 64);
        if (lane >= off) v += n;
    }
    __shared__ int wsum[16];
    __shared__ int woff[16];
    if (lane == 63) wsum[wid] = v;
    __syncthreads();
    if (t < 16) {
        int acc = 0;
        for (int w = 0; w < t; w++) acc += wsum[w];
        woff[t] = acc;
    }
    __syncthreads();
    int run = (v - tsum) + woff[wid];   // exclusive prefix for this thread

    const float* prow = prob + (size_t)b * L_;
    #pragma unroll
    for (int j = 0; j < 8; j++) {
        const int l = base_l + j;
        if (mv[j]) {
            float d = 1.0f - prow[l];
            d = fminf(fmaxf(d, 0.0f), 1.0f);
            pos[(size_t)b * M_ + run] = l;
            dec[(size_t)b * M_ + run] = d;
            run += 1;
        }
    }
}

// ---------------- kernel 2: zero-init segment END values + decay products ---
// One block per (b, segment); 256 threads x f4 = full D row. Fully unrolled so
// the compiler hoists the 16 independent gather loads.
__global__ __launch_bounds__(256)
void segend_kernel(const f4* __restrict__ x4,
                   const int* __restrict__ pos,
                   const float* __restrict__ dec,
                   f4* __restrict__ ez4,
                   float* __restrict__ Aseg) {
    const int blk = blockIdx.x;          // b*S_ + s
    const int b = blk / S_, s = blk % S_;
    const int t = threadIdx.x;
    __shared__ int   pl[G_];
    __shared__ float dl[G_];
    if (t < G_) {
        pl[t] = pos[(size_t)b * M_ + (size_t)s * G_ + t];
        dl[t] = dec[(size_t)b * M_ + (size_t)s * G_ + t];
    }
    __syncthreads();
    f4 h = (f4)(0.0f);
    #pragma unroll
    for (int m = 0; m < G_; m++) {
        const float d = dl[m];
        const f4 xv = x4[((size_t)b * L_ + pl[m]) * D4_ + t];
        h = d * h + (1.0f - d) * xv;
    }
    ez4[(size_t)blk * D4_ + t] = h;
    if (t == 0) {
        float p = 1.0f;
        #pragma unroll
        for (int m = 0; m < G_; m++) p *= dl[m];
        Aseg[blk] = p;
    }
}

// ---------------- kernel 3: carry propagation across segments + new_state ---
// grid (B, 16), block 64: scalar channel per thread (8192 parallel chains).
// ez prefetched in batches of 8 (statically indexed regs) so the serial FMA
// chain stalls once per 8 steps instead of every step.
__global__ __launch_bounds__(64)
void combine_kernel(const float* __restrict__ ez,
                    const float* __restrict__ Aseg,
                    const float* __restrict__ state,
                    float* __restrict__ hinit,
                    float* __restrict__ newstate) {
    const int b = blockIdx.x;
    const int ch = blockIdx.y * 64 + threadIdx.x;   // scalar channel 0..1023
    __shared__ float Al[S_];
    for (int i = threadIdx.x; i < S_; i += 64) Al[i] = Aseg[b * S_ + i];
    __syncthreads();

    float c = state[(size_t)b * D_ + ch];
    for (int s0 = 0; s0 < S_; s0 += 8) {
        float e[8];
        #pragma unroll
        for (int j = 0; j < 8; j++)
            e[j] = ez[((size_t)b * S_ + s0 + j) * D_ + ch];
        #pragma unroll
        for (int j = 0; j < 8; j++) {
            hinit[((size_t)b * S_ + s0 + j) * D_ + ch] = c;
            c = fmaf(Al[s0 + j], c, e[j]);
        }
    }
    newstate[(size_t)b * D_ + ch] = c;   // counts == M guaranteed
}

// ---------------- kernel 4: fused scan + FLAT run-scatter detokenizer -------
// One block (256 threads, full D) per (b, segment). The segment's runs cover
// the contiguous row range [pl[0], pl[G]); iterate it as ONE flat loop,
// software-pipelined in 4-row groups (next group's NT loads issued before the
// current group's stores), advancing the scan state h at run boundaries via a
// uniform scalar branch. Boundary x rows double-prefetched (xn, xn2).
__global__ __launch_bounds__(256)
void fused_kernel(const f4* __restrict__ x4,
                  const f4* __restrict__ res4,
                  const int* __restrict__ pos,
                  const float* __restrict__ dec,
                  const f4* __restrict__ hinit4,
                  f4* __restrict__ out4) {
    const int blk = blockIdx.x;          // b*S_ + s
    const int b = blk / S_, s = blk % S_;
    const int t = threadIdx.x;
    __shared__ int   pl[G_ + 1];
    __shared__ float dl[G_];
    if (t < G_) {
        pl[t] = pos[(size_t)b * M_ + (size_t)s * G_ + t];
        dl[t] = dec[(size_t)b * M_ + (size_t)s * G_ + t];
    }
    if (t == 0) {
        pl[G_] = (s == S_ - 1) ? L_ : pos[(size_t)b * M_ + (size_t)(s + 1) * G_];
    }
    __syncthreads();

    const f4* xrow   = x4   + (size_t)b * L_ * D4_;
    const f4* resrow = res4 + (size_t)b * L_ * D4_;
    f4*       outrow = out4 + (size_t)b * L_ * D4_;

    // prefix [0, pos[0]) of the batch row: ci < 0 -> pure residual (short)
    if (s == 0) {
        const int p0 = pl[0];
        for (int l0 = 0; l0 < p0; l0++) {
            f4 r = __builtin_nontemporal_load(resrow + (size_t)l0 * D4_ + t);
            __builtin_nontemporal_store(r, outrow + (size_t)l0 * D4_ + t);
        }
    }

    f4 h = hinit4[(size_t)blk * D4_ + t];
    int m = -1;                          // current run (none yet)
    int nextb = pl[0];                   // next run-boundary row
    f4 xn  = xrow[(size_t)pl[0] * D4_ + t];   // x at boundary m+1
    f4 xn2 = xrow[(size_t)pl[1] * D4_ + t];   // x at boundary m+2
    int l = pl[0];
    const int lend = pl[G_];

    // advance run state when row l+K is a boundary (uniform across block)
    #define ADV(K, HH)                                                    \
        if (l + (K) == nextb) {                                           \
            ++m;                                                          \
            const float d_ = dl[m];                                       \
            h = d_ * h + (1.0f - d_) * xn;                                \
            xn = xn2;                                                     \
            nextb = pl[m + 1];                                            \
            const int ni_ = (m + 2 <= G_ - 1) ? pl[m + 2] : pl[0];        \
            xn2 = xrow[(size_t)ni_ * D4_ + t];                            \
        }                                                                 \
        HH = h;

    f4 c0, c1, c2, c3;
    if (l + 4 <= lend) {
        c0 = __builtin_nontemporal_load(resrow + (size_t)(l + 0) * D4_ + t);
        c1 = __builtin_nontemporal_load(resrow + (size_t)(l + 1) * D4_ + t);
        c2 = __builtin_nontemporal_load(resrow + (size_t)(l + 2) * D4_ + t);
        c3 = __builtin_nontemporal_load(resrow + (size_t)(l + 3) * D4_ + t);
    }
    while (l + 8 <= lend) {
        f4 n0 = __builtin_nontemporal_load(resrow + (size_t)(l + 4) * D4_ + t);
        f4 n1 = __builtin_nontemporal_load(resrow + (size_t)(l + 5) * D4_ + t);
        f4 n2 = __builtin_nontemporal_load(resrow + (size_t)(l + 6) * D4_ + t);
        f4 n3 = __builtin_nontemporal_load(resrow + (size_t)(l + 7) * D4_ + t);
        f4 h0, h1, h2, h3;
        ADV(0, h0); ADV(1, h1); ADV(2, h2); ADV(3, h3);
        __builtin_nontemporal_store(c0 + h0, outrow + (size_t)(l + 0) * D4_ + t);
        __builtin_nontemporal_store(c1 + h1, outrow + (size_t)(l + 1) * D4_ + t);
        __builtin_nontemporal_store(c2 + h2, outrow + (size_t)(l + 2) * D4_ + t);
        __builtin_nontemporal_store(c3 + h3, outrow + (size_t)(l + 3) * D4_ + t);
        c0 = n0; c1 = n1; c2 = n2; c3 = n3;
        l += 4;
    }
    if (l + 4 <= lend) {
        f4 h0, h1, h2, h3;
        ADV(0, h0); ADV(1, h1); ADV(2, h2); ADV(3, h3);
        __builtin_nontemporal_store(c0 + h0, outrow + (size_t)(l + 0) * D4_ + t);
        __builtin_nontemporal_store(c1 + h1, outrow + (size_t)(l + 1) * D4_ + t);
        __builtin_nontemporal_store(c2 + h2, outrow + (size_t)(l + 2) * D4_ + t);
        __builtin_nontemporal_store(c3 + h3, outrow + (size_t)(l + 3) * D4_ + t);
        l += 4;
    }
    for (; l < lend; l++) {
        f4 hh;
        ADV(0, hh);
        f4 r = __builtin_nontemporal_load(resrow + (size_t)l * D4_ + t);
        __builtin_nontemporal_store(r + hh, outrow + (size_t)l * D4_ + t);
    }
    #undef ADV
}

extern "C" void kernel_launch(void* const* d_in, const int* in_sizes, int n_in,
                              void* d_out, int out_size, void* d_ws, size_t ws_size,
                              hipStream_t stream) {
    const float* x        = (const float*)d_in[0];
    const float* residual = (const float*)d_in[1];
    const float* prob     = (const float*)d_in[2];
    const void*  mask     = d_in[3];
    const float* state    = (const float*)d_in[4];

    float* out       = (float*)d_out;                       // (B,L,D)
    float* new_state = out + (size_t)B_ * L_ * D_;          // (B,D)

    if (ws_size < WS_TOTAL) return;  // fail loudly (zeros) rather than corrupt

    char* ws = (char*)d_ws;
    int*   pos   = (int*)  (ws + OFF_POS);
    float* dec   = (float*)(ws + OFF_DEC);
    float* Aseg  = (float*)(ws + OFF_A);
    float* ez    = (float*)(ws + OFF_EZ);
    float* hinit = (float*)(ws + OFF_HINIT);

    compact_kernel<<<B_, 1024, 0, stream>>>(mask, prob, pos, dec);

    segend_kernel<<<B_ * S_, 256, 0, stream>>>(
        (const f4*)x, pos, dec, (f4*)ez, Aseg);

    combine_kernel<<<dim3(B_, 16), 64, 0, stream>>>(
        ez, Aseg, state, hinit, new_state);

    fused_kernel<<<B_ * S_, 256, 0, stream>>>(
        (const f4*)x, (const f4*)residual, pos, dec,
        (const f4*)hinit, (f4*)out);
}